// Round 11
// baseline (218.004 us; speedup 1.0000x reference)
//
#include <hip/hip_runtime.h>
#include <hip/hip_bf16.h>

// EdgeWeightFromDistance: out[e] = relu(relu([x[src], y[dst], dist] @ W1 + b1) @ W2 + b2)
// E = 1e6, NODE_DIM = 64, HIDDEN = 128.
// R15: R14 refuted the LDS theory cleanly (Wt reads -80%, conflicts 5.5->3.0M, MFMA -20%,
//      dur WORSE 62->70 via occupancy 35->20%). Eliminated: occupancy(R6), bytes(R11),
//      LDS(R14), MFMA count(R14). Last untested-unconfounded theory: idx->gather serial
//      chain. Pipeline attempt #3 with all prior confounds removed:
//      - R6's 8-indep-chain acc core intact (R5's confound: 2 chains, MfmaUtil 20%).
//      - Lean prefetch: idx 2 tiles ahead (8 reg) + frags 1 ahead (32 reg) ONLY.
//        No pos prefetch: R14's no-fold structure consumes dist in the post-MFMA
//        epilogue, so pos loads issued at tile-top hide under the MFMA block free.
//        (R9's confound: fat buffers -> 33 MB spill.)
//      - No lambda / no DPP (container-failure triggers). (256,3), grid 768.
//      Gates: WRITE ~3.9 MB, VGPR <= 170, occupancy >= 25%. If dur ~62 with gates
//      passed -> all axes falsified -> declare latency-equilibrium roofline.

constexpr int NDIM  = 64;
constexpr int HID   = 128;
constexpr int KPAD  = 136;   // bf16 elems per Wt row (chunks 0..15 used)

typedef __attribute__((ext_vector_type(8))) short  short8;
typedef __attribute__((ext_vector_type(4))) int    int4v;
typedef __attribute__((ext_vector_type(4))) float  floatx4;

__device__ __forceinline__ short f2bf(float f) {
    union { __hip_bfloat16 h; short s; } cv;
    cv.h = __float2bfloat16(f);
    return cv.s;
}

__device__ __forceinline__ int pack2(float a, float b) {
    union { __hip_bfloat162 h; int u; } cv;
    cv.h = __float22bfloat162_rn(float2{a, b});
    return cv.u;
}

__device__ __forceinline__ short8 make_afrag_f32(const float* rp) {
    const floatx4 f0 = *reinterpret_cast<const floatx4*>(rp);
    const floatx4 f1 = *reinterpret_cast<const floatx4*>(rp + 4);
    union { int4v i; short8 s8; } cv;
    cv.i.x = pack2(f0.x, f0.y);
    cv.i.y = pack2(f0.z, f0.w);
    cv.i.z = pack2(f1.x, f1.y);
    cv.i.w = pack2(f1.z, f1.w);
    return cv.s8;
}

__device__ __forceinline__ float bf2f(short s) {
    union { __hip_bfloat16 h; short v; } cv;
    cv.v = s;
    return __bfloat162float(cv.h);
}

// ---- streaming fp32 -> bf16 convert of x and y into workspace ----
__global__ __launch_bounds__(256) void cvt_kernel(
    const float* __restrict__ xin, const float* __restrict__ yin,
    short* __restrict__ xb, short* __restrict__ yb, int nfl)
{
    const int stride = gridDim.x * blockDim.x;
    const int n8 = nfl >> 3;
    for (int i = blockIdx.x * blockDim.x + threadIdx.x; i < n8; i += stride) {
        {
            const floatx4 f0 = *reinterpret_cast<const floatx4*>(xin + i * 8);
            const floatx4 f1 = *reinterpret_cast<const floatx4*>(xin + i * 8 + 4);
            union { int4v v; short8 s; } c;
            c.v.x = pack2(f0.x, f0.y); c.v.y = pack2(f0.z, f0.w);
            c.v.z = pack2(f1.x, f1.y); c.v.w = pack2(f1.z, f1.w);
            *reinterpret_cast<short8*>(xb + i * 8) = c.s;
        }
        {
            const floatx4 f0 = *reinterpret_cast<const floatx4*>(yin + i * 8);
            const floatx4 f1 = *reinterpret_cast<const floatx4*>(yin + i * 8 + 4);
            union { int4v v; short8 s; } c;
            c.v.x = pack2(f0.x, f0.y); c.v.y = pack2(f0.z, f0.w);
            c.v.z = pack2(f1.x, f1.y); c.v.w = pack2(f1.z, f1.w);
            *reinterpret_cast<short8*>(yb + i * 8) = c.s;
        }
    }
}

struct IdxB { int s0, d0, s1, d1; };

__device__ __forceinline__ void load_idx(int tile, int wave, int lm, int E,
    const int* __restrict__ srcp, const int* __restrict__ dstp, IdxB& I)
{
    const int mb = tile * 128 + wave * 32;
    int m0 = mb + lm;       if (m0 >= E) m0 = E - 1;
    int m1 = mb + 16 + lm;  if (m1 >= E) m1 = E - 1;
    I.s0 = srcp[m0]; I.d0 = dstp[m0];
    I.s1 = srcp[m1]; I.d1 = dstp[m1];
}

struct FragB { short8 fa[4]; short8 fb[4]; };

template <bool BF16GATHER>
__device__ __forceinline__ void load_frags(const IdxB& I,
    const float* __restrict__ x, const float* __restrict__ y,
    const short* __restrict__ xb, const short* __restrict__ yb,
    int quad, FragB& F)
{
#pragma unroll
    for (int c = 0; c < 4; ++c) {
        const int kk = c * 32 + quad * 8;
        if (BF16GATHER) {
            const short* pa = (c < 2) ? (xb + I.s0 * NDIM + kk)
                                      : (yb + I.d0 * NDIM + (kk - 64));
            const short* pb = (c < 2) ? (xb + I.s1 * NDIM + kk)
                                      : (yb + I.d1 * NDIM + (kk - 64));
            F.fa[c] = *reinterpret_cast<const short8*>(pa);
            F.fb[c] = *reinterpret_cast<const short8*>(pb);
        } else {
            F.fa[c] = make_afrag_f32((c < 2) ? (x + I.s0 * NDIM + kk)
                                             : (y + I.d0 * NDIM + (kk - 64)));
            F.fb[c] = make_afrag_f32((c < 2) ? (x + I.s1 * NDIM + kk)
                                             : (y + I.d1 * NDIM + (kk - 64)));
        }
    }
}

// compute core: R6 8-chain acc + R14 no-fold epilogue (dist consumed post-MFMA)
__device__ __forceinline__ void compute_tile(
    const IdxB& I, const FragB& F, int tile, int E,
    const short* __restrict__ Wt,
    const float* __restrict__ px, const float* __restrict__ py,
    int lane, int lm, int quad, int wave,
    const float* w2v, const float* w1rv, const float* b1v, float b2s,
    float* __restrict__ out)
{
    // pos loads issued here; first USE is after the half-0 MFMA block -> free window
    float pa0 = 0.f, pa1 = 0.f, pa2 = 0.f, pb0 = 0.f, pb1 = 0.f, pb2 = 0.f;
    if (lane < 32) {
        const int ps = (lane < 16) ? I.s0 : I.s1;
        const int pd = (lane < 16) ? I.d0 : I.d1;
        pa0 = px[ps * 3 + 0]; pa1 = px[ps * 3 + 1]; pa2 = px[ps * 3 + 2];
        pb0 = py[pd * 3 + 0]; pb1 = py[pd * 3 + 1]; pb2 = py[pd * 3 + 2];
    }

    float p0 = 0.f, p1 = 0.f, p2 = 0.f, p3 = 0.f;
    float q0 = 0.f, q1 = 0.f, q2 = 0.f, q3 = 0.f;
    float dfA[4], dfB[4];

    int zoff = 0;
    asm volatile("" : "+v"(zoff));
    const short* wr = Wt + zoff + lm * KPAD + quad * 8;

#pragma unroll
    for (int half = 0; half < 2; ++half) {
        if (half) __builtin_amdgcn_sched_barrier(0);

        floatx4 aA[4], aB[4];
#pragma unroll
        for (int u = 0; u < 4; ++u) {
            const float bi = b1v[half * 4 + u];
            aA[u] = floatx4{bi, bi, bi, bi};
            aB[u] = floatx4{bi, bi, bi, bi};
        }
#pragma unroll
        for (int u = 0; u < 4; ++u) {
            const int t = half * 4 + u;
            const short* bp = wr + t * (16 * KPAD);
            const short8 bg0 = *reinterpret_cast<const short8*>(bp);
            const short8 bg1 = *reinterpret_cast<const short8*>(bp + 32);
            const short8 bg2 = *reinterpret_cast<const short8*>(bp + 64);
            const short8 bg3 = *reinterpret_cast<const short8*>(bp + 96);
            aA[u] = __builtin_amdgcn_mfma_f32_16x16x32_bf16(F.fa[0], bg0, aA[u], 0, 0, 0);
            aB[u] = __builtin_amdgcn_mfma_f32_16x16x32_bf16(F.fb[0], bg0, aB[u], 0, 0, 0);
            aA[u] = __builtin_amdgcn_mfma_f32_16x16x32_bf16(F.fa[1], bg1, aA[u], 0, 0, 0);
            aB[u] = __builtin_amdgcn_mfma_f32_16x16x32_bf16(F.fb[1], bg1, aB[u], 0, 0, 0);
            aA[u] = __builtin_amdgcn_mfma_f32_16x16x32_bf16(F.fa[2], bg2, aA[u], 0, 0, 0);
            aB[u] = __builtin_amdgcn_mfma_f32_16x16x32_bf16(F.fb[2], bg2, aB[u], 0, 0, 0);
            aA[u] = __builtin_amdgcn_mfma_f32_16x16x32_bf16(F.fa[3], bg3, aA[u], 0, 0, 0);
            aB[u] = __builtin_amdgcn_mfma_f32_16x16x32_bf16(F.fb[3], bg3, aB[u], 0, 0, 0);
        }
        if (half == 0) {
            // first use of pos: dist + redistribution (waitcnt lands here)
            float dd = 0.f;
            if (lane < 32) {
                const float ax = pa0 - pb0;
                const float ay = pa1 - pb1;
                const float az = pa2 - pb2;
                dd = sqrtf(ax * ax + ay * ay + az * az);
            }
#pragma unroll
            for (int r = 0; r < 4; ++r) {
                dfA[r] = bf2f(f2bf(__shfl(dd, quad * 4 + r, 64)));
                dfB[r] = bf2f(f2bf(__shfl(dd, 16 + quad * 4 + r, 64)));
            }
        }
        // per-half epilogue: + dist*w1r (VALU fold), relu, dot-W2
#pragma unroll
        for (int u = 0; u < 4; ++u) {
            const int t = half * 4 + u;
            const float w   = w2v[t];
            const float wr1 = w1rv[t];
            p0 += fmaxf(fmaf(dfA[0], wr1, aA[u][0]), 0.f) * w;
            p1 += fmaxf(fmaf(dfA[1], wr1, aA[u][1]), 0.f) * w;
            p2 += fmaxf(fmaf(dfA[2], wr1, aA[u][2]), 0.f) * w;
            p3 += fmaxf(fmaf(dfA[3], wr1, aA[u][3]), 0.f) * w;
            q0 += fmaxf(fmaf(dfB[0], wr1, aB[u][0]), 0.f) * w;
            q1 += fmaxf(fmaf(dfB[1], wr1, aB[u][1]), 0.f) * w;
            q2 += fmaxf(fmaf(dfB[2], wr1, aB[u][2]), 0.f) * w;
            q3 += fmaxf(fmaf(dfB[3], wr1, aB[u][3]), 0.f) * w;
        }
    }

#pragma unroll
    for (int off = 1; off < 16; off <<= 1) {
        p0 += __shfl_xor(p0, off, 64);
        p1 += __shfl_xor(p1, off, 64);
        p2 += __shfl_xor(p2, off, 64);
        p3 += __shfl_xor(p3, off, 64);
        q0 += __shfl_xor(q0, off, 64);
        q1 += __shfl_xor(q1, off, 64);
        q2 += __shfl_xor(q2, off, 64);
        q3 += __shfl_xor(q3, off, 64);
    }
    if (lm < 4) {
        const int mb = tile * 128 + wave * 32;
        const float vA = (lm == 0) ? p0 : (lm == 1) ? p1 : (lm == 2) ? p2 : p3;
        const float vB = (lm == 0) ? q0 : (lm == 1) ? q1 : (lm == 2) ? q2 : q3;
        const int eA = mb + quad * 4 + lm;
        const int eB = mb + 16 + quad * 4 + lm;
        if (eA < E) out[eA] = fmaxf(vA + b2s, 0.f);
        if (eB < E) out[eB] = fmaxf(vB + b2s, 0.f);
    }
}

template <bool BF16GATHER>
__global__ __launch_bounds__(256, 3) void edge_mlp_kernel(
    const float* __restrict__ x, const float* __restrict__ y,
    const short* __restrict__ xb, const short* __restrict__ yb,
    const int*  __restrict__ ei, const float* __restrict__ px,
    const float* __restrict__ py, const float* __restrict__ W1,
    const float* __restrict__ b1, const float* __restrict__ W2,
    const float* __restrict__ b2, float* __restrict__ out, int E)
{
    __shared__ __align__(16) short Wt[HID * KPAD];
    const int tid = threadIdx.x;

    for (int base = 0; base < HID * HID; base += 256 * 8) {
        float f[8];
#pragma unroll
        for (int u = 0; u < 8; ++u) f[u] = W1[base + u * 256 + tid];
#pragma unroll
        for (int u = 0; u < 8; ++u) {
            int i = base + u * 256 + tid;
            Wt[(i & 127) * KPAD + (i >> 7)] = f2bf(f[u]);
        }
    }
    __syncthreads();

    const int lane = tid & 63;
    const int wave = tid >> 6;
    const int quad = lane >> 4;
    const int lm   = lane & 15;

    float w2v[8], w1rv[8], b1v[8];
#pragma unroll
    for (int t = 0; t < 8; ++t) {
        const int n = t * 16 + lm;
        w2v[t]  = W2[n];
        w1rv[t] = bf2f(f2bf(W1[128 * HID + n]));   // bf16-rounded, as the fold-MFMA saw it
        b1v[t]  = bf2f(f2bf(b1[n]));
    }
    const float b2s = b2[0];

    const int* __restrict__ srcp = ei;
    const int* __restrict__ dstp = ei + E;

    const int ntiles = (E + 127) / 128;
    const int step = gridDim.x;
    int tile = blockIdx.x;
    if (tile >= ntiles) return;

    // ---- pipeline: idx 2 ahead, frags 1 ahead (all loads clamp-guarded) ----
    IdxB Ic, In; FragB Fa, Fb;
    load_idx(tile, wave, lm, E, srcp, dstp, Ic);
    load_idx(tile + step, wave, lm, E, srcp, dstp, In);
    load_frags<BF16GATHER>(Ic, x, y, xb, yb, quad, Fa);

#pragma unroll 1
    for (;;) {
        // phase A: current tile (Ic, Fa); prefetch frags(t+1) from In; idx(t+2) -> Ic's slot? no:
        // after compute, roles: current <- In/Fb, next-idx <- freshly loaded.
        load_frags<BF16GATHER>(In, x, y, xb, yb, quad, Fb);
        {
            IdxB tmp = Ic;     // current tile's idx (pos needs it inside compute)
            load_idx(tile + 2 * step, wave, lm, E, srcp, dstp, Ic);   // idx(t+2)
            compute_tile(tmp, Fa, tile, E, Wt, px, py, lane, lm, quad, wave,
                         w2v, w1rv, b1v, b2s, out);
        }
        tile += step;
        if (tile >= ntiles) break;

        // phase B: current tile (In, Fb); prefetch frags from Ic (idx t+1); idx(t+2) -> In
        load_frags<BF16GATHER>(Ic, x, y, xb, yb, quad, Fa);
        {
            IdxB tmp = In;
            load_idx(tile + 2 * step, wave, lm, E, srcp, dstp, In);
            compute_tile(tmp, Fb, tile, E, Wt, px, py, lane, lm, quad, wave,
                         w2v, w1rv, b1v, b2s, out);
        }
        tile += step;
        if (tile >= ntiles) break;
    }
}

extern "C" void kernel_launch(void* const* d_in, const int* in_sizes, int n_in,
                              void* d_out, int out_size, void* d_ws, size_t ws_size,
                              hipStream_t stream)
{
    const float* x  = (const float*)d_in[0];
    const float* y  = (const float*)d_in[1];
    const int*   ei = (const int*)  d_in[2];
    const float* px = (const float*)d_in[3];
    const float* py = (const float*)d_in[4];
    const float* W1 = (const float*)d_in[5];
    const float* b1 = (const float*)d_in[6];
    const float* W2 = (const float*)d_in[7];
    const float* b2 = (const float*)d_in[8];
    float* out = (float*)d_out;
    const int E = in_sizes[2] / 2;
    const int nnode_elems = in_sizes[0];             // N_NODES * 64

    const size_t need = (size_t)nnode_elems * 2 * sizeof(short);
    if (ws_size >= need) {
        short* xb = (short*)d_ws;
        short* yb = xb + nnode_elems;
        cvt_kernel<<<dim3(1024), dim3(256), 0, stream>>>(x, y, xb, yb, nnode_elems);
        edge_mlp_kernel<true><<<dim3(768), dim3(256), 0, stream>>>(
            x, y, xb, yb, ei, px, py, W1, b1, W2, b2, out, E);
    } else {
        edge_mlp_kernel<false><<<dim3(768), dim3(256), 0, stream>>>(
            x, y, nullptr, nullptr, ei, px, py, W1, b1, W2, b2, out, E);
    }
}

// Round 12
// 164.660 us; speedup vs baseline: 1.3240x; 1.3240x over previous
//
#include <hip/hip_runtime.h>
#include <hip/hip_bf16.h>

// EdgeWeightFromDistance: out[e] = relu(relu([x[src], y[dst], dist] @ W1 + b1) @ W2 + b2)
// E = 1e6, NODE_DIM = 64, HIDDEN = 128.
// R16: R15 pipeline spilled AGAIN via aggregate->scratch (VGPR 84 but WRITE 69.8 MB —
//      structs in local mem, rule #20). Pipeline attempts: R5 ILP-loss, R9 spill,
//      R15 spill => 1-tile-ahead double-buffer abandoned. R16 = low-risk composite on
//      the verified R6 core (62 µs):
//      (a) gathers issue FIRST in each iteration (idx prefetched as 4 named scalars),
//          removing the ~600-800 cy idx->pos->dist prelude from before the long pole;
//      (b) R14's validated VALU-fold (absmax 0.00390625): pos consumed post-MFMA ->
//          pos loads hide under half-0 MFMA block; -16 MFMA, -8 LDS reads per tile;
//      (c) no structs/lambda/DPP in the loop; statically-indexed arrays only.
//      (256,3), grid 768, ~116 live regs. Gates: WRITE ~3.9 MB, VGPR <= 130.
//      If dur stays ~62 with gates passed -> all mechanisms nulled -> ROOFLINE next.

constexpr int NDIM  = 64;
constexpr int HID   = 128;
constexpr int KPAD  = 136;   // bf16 elems per Wt row (chunks 0..15 used)

typedef __attribute__((ext_vector_type(8))) short  short8;
typedef __attribute__((ext_vector_type(4))) int    int4v;
typedef __attribute__((ext_vector_type(4))) float  floatx4;

__device__ __forceinline__ short f2bf(float f) {
    union { __hip_bfloat16 h; short s; } cv;
    cv.h = __float2bfloat16(f);
    return cv.s;
}

__device__ __forceinline__ int pack2(float a, float b) {
    union { __hip_bfloat162 h; int u; } cv;
    cv.h = __float22bfloat162_rn(float2{a, b});
    return cv.u;
}

__device__ __forceinline__ short8 make_afrag_f32(const float* rp) {
    const floatx4 f0 = *reinterpret_cast<const floatx4*>(rp);
    const floatx4 f1 = *reinterpret_cast<const floatx4*>(rp + 4);
    union { int4v i; short8 s8; } cv;
    cv.i.x = pack2(f0.x, f0.y);
    cv.i.y = pack2(f0.z, f0.w);
    cv.i.z = pack2(f1.x, f1.y);
    cv.i.w = pack2(f1.z, f1.w);
    return cv.s8;
}

__device__ __forceinline__ float bf2f(short s) {
    union { __hip_bfloat16 h; short v; } cv;
    cv.v = s;
    return __bfloat162float(cv.h);
}

// ---- streaming fp32 -> bf16 convert of x and y into workspace ----
__global__ __launch_bounds__(256) void cvt_kernel(
    const float* __restrict__ xin, const float* __restrict__ yin,
    short* __restrict__ xb, short* __restrict__ yb, int nfl)
{
    const int stride = gridDim.x * blockDim.x;
    const int n8 = nfl >> 3;
    for (int i = blockIdx.x * blockDim.x + threadIdx.x; i < n8; i += stride) {
        {
            const floatx4 f0 = *reinterpret_cast<const floatx4*>(xin + i * 8);
            const floatx4 f1 = *reinterpret_cast<const floatx4*>(xin + i * 8 + 4);
            union { int4v v; short8 s; } c;
            c.v.x = pack2(f0.x, f0.y); c.v.y = pack2(f0.z, f0.w);
            c.v.z = pack2(f1.x, f1.y); c.v.w = pack2(f1.z, f1.w);
            *reinterpret_cast<short8*>(xb + i * 8) = c.s;
        }
        {
            const floatx4 f0 = *reinterpret_cast<const floatx4*>(yin + i * 8);
            const floatx4 f1 = *reinterpret_cast<const floatx4*>(yin + i * 8 + 4);
            union { int4v v; short8 s; } c;
            c.v.x = pack2(f0.x, f0.y); c.v.y = pack2(f0.z, f0.w);
            c.v.z = pack2(f1.x, f1.y); c.v.w = pack2(f1.z, f1.w);
            *reinterpret_cast<short8*>(yb + i * 8) = c.s;
        }
    }
}

template <bool BF16GATHER>
__global__ __launch_bounds__(256, 3) void edge_mlp_kernel(
    const float* __restrict__ x, const float* __restrict__ y,
    const short* __restrict__ xb, const short* __restrict__ yb,
    const int*  __restrict__ ei, const float* __restrict__ px,
    const float* __restrict__ py, const float* __restrict__ W1,
    const float* __restrict__ b1, const float* __restrict__ W2,
    const float* __restrict__ b2, float* __restrict__ out, int E)
{
    __shared__ __align__(16) short Wt[HID * KPAD];   // W1^T [n][k] bf16 (chunks 0..15)
    const int tid = threadIdx.x;

    for (int base = 0; base < HID * HID; base += 256 * 8) {
        float f[8];
#pragma unroll
        for (int u = 0; u < 8; ++u) f[u] = W1[base + u * 256 + tid];
#pragma unroll
        for (int u = 0; u < 8; ++u) {
            int i = base + u * 256 + tid;
            Wt[(i & 127) * KPAD + (i >> 7)] = f2bf(f[u]);
        }
    }
    __syncthreads();

    const int lane = tid & 63;
    const int wave = tid >> 6;
    const int quad = lane >> 4;
    const int lm   = lane & 15;   // A-frag row m; B-frag/C-D col n (within tile)

    float w2v[8], w1rv[8], b1v[8];
#pragma unroll
    for (int t = 0; t < 8; ++t) {
        const int n = t * 16 + lm;
        w2v[t]  = W2[n];
        w1rv[t] = bf2f(f2bf(W1[128 * HID + n]));   // bf16-rounded, as the fold-MFMA saw it
        b1v[t]  = bf2f(f2bf(b1[n]));
    }
    const float b2s = b2[0];

    const int* __restrict__ srcp = ei;
    const int* __restrict__ dstp = ei + E;

    const int ntiles = (E + 127) / 128;       // 128 edges per block-iter, 32 per wave
    const int step = gridDim.x;
    int tile = blockIdx.x;
    if (tile >= ntiles) return;

    // ---- prologue: load current tile's idx (named scalars, clamp-guarded) ----
    int cs0, cd0, cs1, cd1;
    {
        const int mb = tile * 128 + wave * 32;
        int m0 = mb + lm;       if (m0 >= E) m0 = E - 1;
        int m1 = mb + 16 + lm;  if (m1 >= E) m1 = E - 1;
        cs0 = srcp[m0]; cd0 = dstp[m0];
        cs1 = srcp[m1]; cd1 = dstp[m1];
    }

#pragma unroll 1
    for (;;) {
        const int mb = tile * 128 + wave * 32;

        // ---- (1) gathers FIRST: the long pole issues at cycle ~0 ----
        short8 fa[4], fb[4];
#pragma unroll
        for (int c = 0; c < 4; ++c) {
            const int kk = c * 32 + quad * 8;
            if (BF16GATHER) {
                const short* pa = (c < 2) ? (xb + cs0 * NDIM + kk)
                                          : (yb + cd0 * NDIM + (kk - 64));
                const short* pb = (c < 2) ? (xb + cs1 * NDIM + kk)
                                          : (yb + cd1 * NDIM + (kk - 64));
                fa[c] = *reinterpret_cast<const short8*>(pa);
                fb[c] = *reinterpret_cast<const short8*>(pb);
            } else {
                fa[c] = make_afrag_f32((c < 2) ? (x + cs0 * NDIM + kk)
                                               : (y + cd0 * NDIM + (kk - 64)));
                fb[c] = make_afrag_f32((c < 2) ? (x + cs1 * NDIM + kk)
                                               : (y + cd1 * NDIM + (kk - 64)));
            }
        }

        // ---- (2) pos loads (consumed post-MFMA; hide under half-0 MFMA block) ----
        float pa0 = 0.f, pa1 = 0.f, pa2 = 0.f, pb0 = 0.f, pb1 = 0.f, pb2 = 0.f;
        if (lane < 32) {
            const int ps = (lane < 16) ? cs0 : cs1;
            const int pd = (lane < 16) ? cd0 : cd1;
            pa0 = px[ps * 3 + 0]; pa1 = px[ps * 3 + 1]; pa2 = px[ps * 3 + 2];
            pb0 = py[pd * 3 + 0]; pb1 = py[pd * 3 + 1]; pb2 = py[pd * 3 + 2];
        }

        // ---- (3) next-tile idx prefetch (named scalars; clamp makes it always safe) ----
        const int ntile = tile + step;
        int ns0, nd0, ns1, nd1;
        {
            const int nmb = ntile * 128 + wave * 32;
            int m0 = nmb + lm;       if (m0 >= E) m0 = E - 1;
            int m1 = nmb + 16 + lm;  if (m1 >= E) m1 = E - 1;
            ns0 = srcp[m0]; nd0 = dstp[m0];
            ns1 = srcp[m1]; nd1 = dstp[m1];
        }

        float p0 = 0.f, p1 = 0.f, p2 = 0.f, p3 = 0.f;
        float q0 = 0.f, q1 = 0.f, q2 = 0.f, q3 = 0.f;
        float dfA[4], dfB[4];

        int zoff = 0;
        asm volatile("" : "+v"(zoff));
        const short* wr = Wt + zoff + lm * KPAD + quad * 8;

#pragma unroll
        for (int half = 0; half < 2; ++half) {
            if (half) __builtin_amdgcn_sched_barrier(0);

            floatx4 aA[4], aB[4];
#pragma unroll
            for (int u = 0; u < 4; ++u) {
                const float bi = b1v[half * 4 + u];
                aA[u] = floatx4{bi, bi, bi, bi};   // b1 in accumulator init
                aB[u] = floatx4{bi, bi, bi, bi};
            }
#pragma unroll
            for (int u = 0; u < 4; ++u) {
                const int t = half * 4 + u;
                const short* bp = wr + t * (16 * KPAD);
                const short8 bg0 = *reinterpret_cast<const short8*>(bp);
                const short8 bg1 = *reinterpret_cast<const short8*>(bp + 32);
                const short8 bg2 = *reinterpret_cast<const short8*>(bp + 64);
                const short8 bg3 = *reinterpret_cast<const short8*>(bp + 96);
                aA[u] = __builtin_amdgcn_mfma_f32_16x16x32_bf16(fa[0], bg0, aA[u], 0, 0, 0);
                aB[u] = __builtin_amdgcn_mfma_f32_16x16x32_bf16(fb[0], bg0, aB[u], 0, 0, 0);
                aA[u] = __builtin_amdgcn_mfma_f32_16x16x32_bf16(fa[1], bg1, aA[u], 0, 0, 0);
                aB[u] = __builtin_amdgcn_mfma_f32_16x16x32_bf16(fb[1], bg1, aB[u], 0, 0, 0);
                aA[u] = __builtin_amdgcn_mfma_f32_16x16x32_bf16(fa[2], bg2, aA[u], 0, 0, 0);
                aB[u] = __builtin_amdgcn_mfma_f32_16x16x32_bf16(fb[2], bg2, aB[u], 0, 0, 0);
                aA[u] = __builtin_amdgcn_mfma_f32_16x16x32_bf16(fa[3], bg3, aA[u], 0, 0, 0);
                aB[u] = __builtin_amdgcn_mfma_f32_16x16x32_bf16(fb[3], bg3, aB[u], 0, 0, 0);
            }
            if (half == 0) {
                // first use of pos: dist + redistribution (pos waitcnt lands here,
                // after the half-0 MFMA block has covered the load latency)
                float dd = 0.f;
                if (lane < 32) {
                    const float ax = pa0 - pb0;
                    const float ay = pa1 - pb1;
                    const float az = pa2 - pb2;
                    dd = sqrtf(ax * ax + ay * ay + az * az);
                }
#pragma unroll
                for (int r = 0; r < 4; ++r) {
                    dfA[r] = bf2f(f2bf(__shfl(dd, quad * 4 + r, 64)));
                    dfB[r] = bf2f(f2bf(__shfl(dd, 16 + quad * 4 + r, 64)));
                }
            }
            // per-half epilogue: + dist*w1r (VALU fold), relu, dot-W2
#pragma unroll
            for (int u = 0; u < 4; ++u) {
                const int t = half * 4 + u;
                const float w   = w2v[t];
                const float wr1 = w1rv[t];
                p0 += fmaxf(fmaf(dfA[0], wr1, aA[u][0]), 0.f) * w;
                p1 += fmaxf(fmaf(dfA[1], wr1, aA[u][1]), 0.f) * w;
                p2 += fmaxf(fmaf(dfA[2], wr1, aA[u][2]), 0.f) * w;
                p3 += fmaxf(fmaf(dfA[3], wr1, aA[u][3]), 0.f) * w;
                q0 += fmaxf(fmaf(dfB[0], wr1, aB[u][0]), 0.f) * w;
                q1 += fmaxf(fmaf(dfB[1], wr1, aB[u][1]), 0.f) * w;
                q2 += fmaxf(fmaf(dfB[2], wr1, aB[u][2]), 0.f) * w;
                q3 += fmaxf(fmaf(dfB[3], wr1, aB[u][3]), 0.f) * w;
            }
        }

        // ---- 16-lane reduce via __shfl_xor butterfly (R4/R6-proven) ----
#pragma unroll
        for (int off = 1; off < 16; off <<= 1) {
            p0 += __shfl_xor(p0, off, 64);
            p1 += __shfl_xor(p1, off, 64);
            p2 += __shfl_xor(p2, off, 64);
            p3 += __shfl_xor(p3, off, 64);
            q0 += __shfl_xor(q0, off, 64);
            q1 += __shfl_xor(q1, off, 64);
            q2 += __shfl_xor(q2, off, 64);
            q3 += __shfl_xor(q3, off, 64);
        }
        if (lm < 4) {
            const float vA = (lm == 0) ? p0 : (lm == 1) ? p1 : (lm == 2) ? p2 : p3;
            const float vB = (lm == 0) ? q0 : (lm == 1) ? q1 : (lm == 2) ? q2 : q3;
            const int eA = mb + quad * 4 + lm;
            const int eB = mb + 16 + quad * 4 + lm;
            if (eA < E) out[eA] = fmaxf(vA + b2s, 0.f);
            if (eB < E) out[eB] = fmaxf(vB + b2s, 0.f);
        }

        tile = ntile;
        if (tile >= ntiles) break;
        cs0 = ns0; cd0 = nd0; cs1 = ns1; cd1 = nd1;
    }
}

extern "C" void kernel_launch(void* const* d_in, const int* in_sizes, int n_in,
                              void* d_out, int out_size, void* d_ws, size_t ws_size,
                              hipStream_t stream)
{
    const float* x  = (const float*)d_in[0];
    const float* y  = (const float*)d_in[1];
    const int*   ei = (const int*)  d_in[2];
    const float* px = (const float*)d_in[3];
    const float* py = (const float*)d_in[4];
    const float* W1 = (const float*)d_in[5];
    const float* b1 = (const float*)d_in[6];
    const float* W2 = (const float*)d_in[7];
    const float* b2 = (const float*)d_in[8];
    float* out = (float*)d_out;
    const int E = in_sizes[2] / 2;
    const int nnode_elems = in_sizes[0];             // N_NODES * 64

    const size_t need = (size_t)nnode_elems * 2 * sizeof(short);
    if (ws_size >= need) {
        short* xb = (short*)d_ws;
        short* yb = xb + nnode_elems;
        cvt_kernel<<<dim3(1024), dim3(256), 0, stream>>>(x, y, xb, yb, nnode_elems);
        edge_mlp_kernel<true><<<dim3(768), dim3(256), 0, stream>>>(
            x, y, xb, yb, ei, px, py, W1, b1, W2, b2, out, E);
    } else {
        edge_mlp_kernel<false><<<dim3(768), dim3(256), 0, stream>>>(
            x, y, nullptr, nullptr, ei, px, py, W1, b1, W2, b2, out, E);
    }
}

// Round 13
// 163.233 us; speedup vs baseline: 1.3355x; 1.0087x over previous
//
#include <hip/hip_runtime.h>
#include <hip/hip_bf16.h>

// EdgeWeightFromDistance: out[e] = relu(relu([x[src], y[dst], dist] @ W1 + b1) @ W2 + b2)
// E = 1e6, NODE_DIM = 64, HIDDEN = 128.
// R17 == R6 restored verbatim (best verified: 62 µs kernel / 163.3 µs harness).
// Session elimination record (13 measured rounds):
//   occupancy 27->35% (R6): null. bytes -37% (R11): null. LDS -80% (R14): worse.
//   MFMA -20% (R14): worse. pipelines (R5/R9/R15): ILP-loss or aggregate-spill.
//   front-loaded gathers (R16): -24%. XCD sort (R10/R11): main kernel unchanged.
// Conclusion: latency equilibrium of the dependent idx->gather chain; counters
// (MfmaUtil 26, VALUBusy 39, HBM 35%, nothing saturated) are the chain-latency
// signature. This is the floor for this structure — expect ROOFLINE declaration.

constexpr int NDIM  = 64;
constexpr int HID   = 128;
constexpr int KPAD  = 136;   // bf16 elems per Wt row: 128 data + w1r + b1 + 6 zeros

typedef __attribute__((ext_vector_type(8))) short  short8;
typedef __attribute__((ext_vector_type(4))) int    int4v;
typedef __attribute__((ext_vector_type(4))) float  floatx4;

__device__ __forceinline__ short f2bf(float f) {
    union { __hip_bfloat16 h; short s; } cv;
    cv.h = __float2bfloat16(f);
    return cv.s;
}

__device__ __forceinline__ int pack2(float a, float b) {
    union { __hip_bfloat162 h; int u; } cv;
    cv.h = __float22bfloat162_rn(float2{a, b});
    return cv.u;
}

__device__ __forceinline__ short8 make_afrag_f32(const float* rp) {
    const floatx4 f0 = *reinterpret_cast<const floatx4*>(rp);
    const floatx4 f1 = *reinterpret_cast<const floatx4*>(rp + 4);
    union { int4v i; short8 s8; } cv;
    cv.i.x = pack2(f0.x, f0.y);
    cv.i.y = pack2(f0.z, f0.w);
    cv.i.z = pack2(f1.x, f1.y);
    cv.i.w = pack2(f1.z, f1.w);
    return cv.s8;
}

// ---- streaming fp32 -> bf16 convert of x and y into workspace ----
__global__ __launch_bounds__(256) void cvt_kernel(
    const float* __restrict__ xin, const float* __restrict__ yin,
    short* __restrict__ xb, short* __restrict__ yb, int nfl)
{
    const int stride = gridDim.x * blockDim.x;
    const int n8 = nfl >> 3;
    for (int i = blockIdx.x * blockDim.x + threadIdx.x; i < n8; i += stride) {
        {
            const floatx4 f0 = *reinterpret_cast<const floatx4*>(xin + i * 8);
            const floatx4 f1 = *reinterpret_cast<const floatx4*>(xin + i * 8 + 4);
            union { int4v v; short8 s; } c;
            c.v.x = pack2(f0.x, f0.y); c.v.y = pack2(f0.z, f0.w);
            c.v.z = pack2(f1.x, f1.y); c.v.w = pack2(f1.z, f1.w);
            *reinterpret_cast<short8*>(xb + i * 8) = c.s;
        }
        {
            const floatx4 f0 = *reinterpret_cast<const floatx4*>(yin + i * 8);
            const floatx4 f1 = *reinterpret_cast<const floatx4*>(yin + i * 8 + 4);
            union { int4v v; short8 s; } c;
            c.v.x = pack2(f0.x, f0.y); c.v.y = pack2(f0.z, f0.w);
            c.v.z = pack2(f1.x, f1.y); c.v.w = pack2(f1.z, f1.w);
            *reinterpret_cast<short8*>(yb + i * 8) = c.s;
        }
    }
}

template <bool BF16GATHER>
__global__ __launch_bounds__(256, 4) void edge_mlp_kernel(
    const float* __restrict__ x, const float* __restrict__ y,
    const short* __restrict__ xb, const short* __restrict__ yb,
    const int*  __restrict__ ei, const float* __restrict__ px,
    const float* __restrict__ py, const float* __restrict__ W1,
    const float* __restrict__ b1, const float* __restrict__ W2,
    const float* __restrict__ b2, float* __restrict__ out, int E)
{
    __shared__ __align__(16) short Wt[HID * KPAD];

    const int tid = threadIdx.x;

    // ---- stage W1[0:128][0:128] transposed into LDS ----
    for (int base = 0; base < HID * HID; base += 256 * 8) {
        float f[8];
#pragma unroll
        for (int u = 0; u < 8; ++u) f[u] = W1[base + u * 256 + tid];
#pragma unroll
        for (int u = 0; u < 8; ++u) {
            int i = base + u * 256 + tid;
            Wt[(i & 127) * KPAD + (i >> 7)] = f2bf(f[u]);
        }
    }
    // fold rows: k=128 -> w1r (dist coeff), k=129 -> b1, k=130..135 -> 0
    if (tid < HID) {
        const int n = tid;
        Wt[n * KPAD + 128] = f2bf(W1[128 * HID + n]);
        Wt[n * KPAD + 129] = f2bf(b1[n]);
#pragma unroll
        for (int j = 130; j < 136; ++j) Wt[n * KPAD + j] = 0;
    }
    __syncthreads();

    const int lane = tid & 63;
    const int wave = tid >> 6;
    const int quad = lane >> 4;
    const int lm   = lane & 15;   // A-frag row m; B-frag/C-D col n (within tile)

    float w2v[8];
#pragma unroll
    for (int t = 0; t < 8; ++t) w2v[t] = W2[t * 16 + lm];
    const float b2s = b2[0];

    const int* __restrict__ srcp = ei;
    const int* __restrict__ dstp = ei + E;

    const int sel5 = (quad == 0) ? 128 : 0;   // fold-step k-offset

    const int ntiles = (E + 127) / 128;       // 128 edges per block-iter, 32 per wave
    for (int tile = blockIdx.x; tile < ntiles; tile += gridDim.x) {
        const int mb = tile * 128 + wave * 32;
        int m0 = mb + lm;       if (m0 >= E) m0 = E - 1;
        int m1 = mb + 16 + lm;  if (m1 >= E) m1 = E - 1;
        const int src0 = srcp[m0], dst0 = dstp[m0];
        const int src1 = srcp[m1], dst1 = dstp[m1];

        // ---- pos + dist: lanes 0..31 each own edge mb+lane ----
        float dd = 0.f;
        if (lane < 32) {
            const int ps = (lane < 16) ? src0 : src1;
            const int pd = (lane < 16) ? dst0 : dst1;
            const float ax = px[ps * 3 + 0] - py[pd * 3 + 0];
            const float ay = px[ps * 3 + 1] - py[pd * 3 + 1];
            const float az = px[ps * 3 + 2] - py[pd * 3 + 2];
            dd = sqrtf(ax * ax + ay * ay + az * az);
        }
        const float dist0 = __shfl(dd, lm, 64);
        const float dist1 = __shfl(dd, lm + 16, 64);

        // ---- A fragments: row m, k = s*32 + quad*8 + j ----
        short8 fa[4], fb[4];
#pragma unroll
        for (int s = 0; s < 4; ++s) {
            const int kk = s * 32 + quad * 8;
            if (BF16GATHER) {
                const short* pa = (s < 2) ? (xb + src0 * NDIM + kk)
                                          : (yb + dst0 * NDIM + (kk - 64));
                const short* pb = (s < 2) ? (xb + src1 * NDIM + kk)
                                          : (yb + dst1 * NDIM + (kk - 64));
                fa[s] = *reinterpret_cast<const short8*>(pa);
                fb[s] = *reinterpret_cast<const short8*>(pb);
            } else {
                fa[s] = make_afrag_f32((s < 2) ? (x + src0 * NDIM + kk)
                                               : (y + dst0 * NDIM + (kk - 64)));
                fb[s] = make_afrag_f32((s < 2) ? (x + src1 * NDIM + kk)
                                               : (y + dst1 * NDIM + (kk - 64)));
            }
        }
        // fold-step A: k=128 -> dist, k=129 -> 1.0 (quad 0 only; others zero)
        short8 fa4, fb4;
        {
            union { int4v i; short8 s8; } ca, cb;
            const int d0 = (quad == 0) ? pack2(dist0, 1.0f) : 0;
            const int d1 = (quad == 0) ? pack2(dist1, 1.0f) : 0;
            ca.i = int4v{d0, 0, 0, 0};
            cb.i = int4v{d1, 0, 0, 0};
            fa4 = ca.s8; fb4 = cb.s8;
        }

        float p0 = 0.f, p1 = 0.f, p2 = 0.f, p3 = 0.f;
        float q0 = 0.f, q1 = 0.f, q2 = 0.f, q3 = 0.f;

        // zoff guard defeats LICM (keeps B-frags re-read from LDS, regs low)
        int zoff = 0;
        asm volatile("" : "+v"(zoff));
        const short* wr  = Wt + zoff + lm * KPAD + quad * 8;
        const short* wr5 = Wt + zoff + lm * KPAD + sel5;

        // ---- two halves of 4 n-tiles each; acc[4][2] live per half (32 AGPR) ----
#pragma unroll
        for (int half = 0; half < 2; ++half) {
            if (half) __builtin_amdgcn_sched_barrier(0);

            floatx4 aA[4], aB[4];
#pragma unroll
            for (int u = 0; u < 4; ++u) {
                aA[u] = floatx4{0.f, 0.f, 0.f, 0.f};
                aB[u] = floatx4{0.f, 0.f, 0.f, 0.f};
            }
#pragma unroll
            for (int u = 0; u < 4; ++u) {
                const int t = half * 4 + u;
                const short* base = wr + t * (16 * KPAD);
                const short8 bg0 = *reinterpret_cast<const short8*>(base);
                const short8 bg1 = *reinterpret_cast<const short8*>(base + 32);
                const short8 bg2 = *reinterpret_cast<const short8*>(base + 64);
                const short8 bg3 = *reinterpret_cast<const short8*>(base + 96);
                const short8 bg4 = *reinterpret_cast<const short8*>(wr5 + t * (16 * KPAD));
                aA[u] = __builtin_amdgcn_mfma_f32_16x16x32_bf16(fa[0], bg0, aA[u], 0, 0, 0);
                aB[u] = __builtin_amdgcn_mfma_f32_16x16x32_bf16(fb[0], bg0, aB[u], 0, 0, 0);
                aA[u] = __builtin_amdgcn_mfma_f32_16x16x32_bf16(fa[1], bg1, aA[u], 0, 0, 0);
                aB[u] = __builtin_amdgcn_mfma_f32_16x16x32_bf16(fb[1], bg1, aB[u], 0, 0, 0);
                aA[u] = __builtin_amdgcn_mfma_f32_16x16x32_bf16(fa[2], bg2, aA[u], 0, 0, 0);
                aB[u] = __builtin_amdgcn_mfma_f32_16x16x32_bf16(fb[2], bg2, aB[u], 0, 0, 0);
                aA[u] = __builtin_amdgcn_mfma_f32_16x16x32_bf16(fa[3], bg3, aA[u], 0, 0, 0);
                aB[u] = __builtin_amdgcn_mfma_f32_16x16x32_bf16(fb[3], bg3, aB[u], 0, 0, 0);
                aA[u] = __builtin_amdgcn_mfma_f32_16x16x32_bf16(fa4,   bg4, aA[u], 0, 0, 0);
                aB[u] = __builtin_amdgcn_mfma_f32_16x16x32_bf16(fb4,   bg4, aB[u], 0, 0, 0);
            }
            // epilogue slice for this half: relu + dot-W2 (t order preserved)
#pragma unroll
            for (int u = 0; u < 4; ++u) {
                const float w = w2v[half * 4 + u];
                p0 += fmaxf(aA[u][0], 0.f) * w;
                p1 += fmaxf(aA[u][1], 0.f) * w;
                p2 += fmaxf(aA[u][2], 0.f) * w;
                p3 += fmaxf(aA[u][3], 0.f) * w;
                q0 += fmaxf(aB[u][0], 0.f) * w;
                q1 += fmaxf(aB[u][1], 0.f) * w;
                q2 += fmaxf(aB[u][2], 0.f) * w;
                q3 += fmaxf(aB[u][3], 0.f) * w;
            }
        }

        // ---- quad-group reduce, +b2, relu, store ----
#pragma unroll
        for (int off = 1; off < 16; off <<= 1) {
            p0 += __shfl_xor(p0, off, 64);
            p1 += __shfl_xor(p1, off, 64);
            p2 += __shfl_xor(p2, off, 64);
            p3 += __shfl_xor(p3, off, 64);
            q0 += __shfl_xor(q0, off, 64);
            q1 += __shfl_xor(q1, off, 64);
            q2 += __shfl_xor(q2, off, 64);
            q3 += __shfl_xor(q3, off, 64);
        }
        if (lm < 4) {
            const float vA = (lm == 0) ? p0 : (lm == 1) ? p1 : (lm == 2) ? p2 : p3;
            const float vB = (lm == 0) ? q0 : (lm == 1) ? q1 : (lm == 2) ? q2 : q3;
            const int eA = mb + quad * 4 + lm;
            const int eB = mb + 16 + quad * 4 + lm;
            if (eA < E) out[eA] = fmaxf(vA + b2s, 0.f);
            if (eB < E) out[eB] = fmaxf(vB + b2s, 0.f);
        }
    }
}

extern "C" void kernel_launch(void* const* d_in, const int* in_sizes, int n_in,
                              void* d_out, int out_size, void* d_ws, size_t ws_size,
                              hipStream_t stream)
{
    const float* x  = (const float*)d_in[0];
    const float* y  = (const float*)d_in[1];
    const int*   ei = (const int*)  d_in[2];
    const float* px = (const float*)d_in[3];
    const float* py = (const float*)d_in[4];
    const float* W1 = (const float*)d_in[5];
    const float* b1 = (const float*)d_in[6];
    const float* W2 = (const float*)d_in[7];
    const float* b2 = (const float*)d_in[8];
    float* out = (float*)d_out;
    const int E = in_sizes[2] / 2;
    const int nnode_elems = in_sizes[0];             // N_NODES * 64

    const size_t need = (size_t)nnode_elems * 2 * sizeof(short);
    if (ws_size >= need) {
        short* xb = (short*)d_ws;
        short* yb = xb + nnode_elems;
        cvt_kernel<<<dim3(1024), dim3(256), 0, stream>>>(x, y, xb, yb, nnode_elems);
        edge_mlp_kernel<true><<<dim3(1024), dim3(256), 0, stream>>>(
            x, y, xb, yb, ei, px, py, W1, b1, W2, b2, out, E);
    } else {
        edge_mlp_kernel<false><<<dim3(1024), dim3(256), 0, stream>>>(
            x, y, nullptr, nullptr, ei, px, py, W1, b1, W2, b2, out, E);
    }
}